// Round 13
// baseline (691.029 us; speedup 1.0000x reference)
//
#include <hip/hip_runtime.h>

typedef __attribute__((ext_vector_type(8))) short short8;
typedef __attribute__((ext_vector_type(4))) float f32x4;

#define BB 16
#define MM 2048
#define NN 2048

static __device__ __forceinline__ unsigned int cvtpk(float lo, float hi) {
  unsigned int r;
  asm("v_cvt_pk_bf16_f32 %0, %1, %2" : "=v"(r) : "v"(lo), "v"(hi));
  return r;
}
static __device__ __forceinline__ float rdlane(float v, int l) {
  return __uint_as_float(__builtin_amdgcn_readlane(__float_as_uint(v), l));
}

// in: [B, nrows, 64] f32 -> out: [B, 64, nrows] bf16
__global__ void transpose_cvt(const float* __restrict__ in,
                              unsigned short* __restrict__ out, int nrows) {
  __shared__ float t[64][65];
  int b = blockIdx.y;
  int n0 = blockIdx.x * 64;
  int tid = threadIdx.x;
  int lane = tid & 63;
  int q = tid >> 6;
  const float* inb = in + ((size_t)b * nrows + n0) * 64;
#pragma unroll
  for (int i = 0; i < 16; ++i) {
    int n = q * 16 + i;
    t[n][lane] = inb[n * 64 + lane];
  }
  __syncthreads();
  unsigned short* outb = out + (size_t)b * 64 * nrows + n0;
  int pr = tid & 31, rq = tid >> 5;
#pragma unroll
  for (int i = 0; i < 8; ++i) {
    int r = rq + 8 * i;
    int n = 2 * pr;
    *(unsigned int*)(outb + (size_t)r * nrows + n) = cvtpk(t[n][r], t[n + 1][r]);
  }
}

// Gram: bmat[b] = T * T^T, T = [64, K] bf16 row-major. grid (B), block 256.
__global__ void gemm_gram2(const unsigned short* __restrict__ tT,
                           float* __restrict__ bmat, int K) {
  __shared__ float part[4][64][65];
  int b = blockIdx.x;
  int tid = threadIdx.x;
  int w = tid >> 6, l = tid & 63;
  int lr = l & 15, g = l >> 4;
  const unsigned short* vb = tT + (size_t)b * 64 * K;
  int kslice = K >> 2;
  int kbase = w * kslice;
  f32x4 acc[4][4] = {};
  for (int kk = 0; kk < kslice; kk += 32) {
    int k = kbase + kk + 8 * g;
    short8 fr[4];
#pragma unroll
    for (int rt = 0; rt < 4; ++rt)
      fr[rt] = *(const short8*)(vb + (size_t)(rt * 16 + lr) * K + k);
#pragma unroll
    for (int rt = 0; rt < 4; ++rt)
#pragma unroll
      for (int ct = 0; ct < 4; ++ct)
        acc[rt][ct] = __builtin_amdgcn_mfma_f32_16x16x32_bf16(fr[rt], fr[ct], acc[rt][ct], 0, 0, 0);
  }
#pragma unroll
  for (int rt = 0; rt < 4; ++rt)
#pragma unroll
    for (int ct = 0; ct < 4; ++ct)
#pragma unroll
      for (int j = 0; j < 4; ++j)
        part[w][rt * 16 + 4 * g + j][ct * 16 + lr] = acc[rt][ct][j];
  __syncthreads();
  float* bb = bmat + b * 4096;
  for (int i = tid; i < 4096; i += 256) {
    int row = i >> 6, col = i & 63;
    bb[i] = part[0][row][col] + part[1][row][col] + part[2][row][col] + part[3][row][col];
  }
}

// a[b][m][r] = sum_n x[b][m][n] * v[b][n][r];  vT = [B,64,N] bf16  (r9 body)
__global__ void __launch_bounds__(256, 2)
gemm_xv(const float* __restrict__ x,
        const unsigned short* __restrict__ vT,
        float* __restrict__ a) {
  __shared__ char smem[32768];
  int b = blockIdx.y;
  int m0 = blockIdx.x * 64;
  int tid = threadIdx.x;
  int w = tid >> 6, l = tid & 63;
  int lr = l & 15, g = l >> 4;
  const unsigned short* vb = vT + (size_t)b * 64 * NN;
  const char* xg0 = (const char*)x + ((size_t)b * MM + m0) * (size_t)(NN * 4);
  f32x4 acc[4] = {};
  int rowb = (w * 16 + lr) * 256;
  int key = lr & 7;

#define XVSTAGE(DB, CH)                                                         \
  {                                                                             \
    char* lbs = (char*)smem + (DB)*16384;                                       \
    _Pragma("unroll")                                                           \
    for (int i = 0; i < 4; ++i) {                                               \
      int s = w * 4 + i;                                                        \
      int lg = ((l & 15) ^ ((s & 1) * 4 + (l >> 4))) * 16;                      \
      const char* gp = xg0 + (size_t)(s * 4 + (l >> 4)) * (NN * 4) +            \
                       (CH)*256 + lg;                                           \
      __builtin_amdgcn_global_load_lds(                                         \
          (const __attribute__((address_space(1))) unsigned int*)gp,            \
          (__attribute__((address_space(3))) unsigned int*)(lbs + s * 1024),    \
          16, 0, 0);                                                            \
    }                                                                           \
  }

  XVSTAGE(0, 0);
  __syncthreads();
  for (int c = 0; c < 32; ++c) {
    int db = c & 1;
    if (c + 1 < 32) XVSTAGE(db ^ 1, c + 1);
    const char* lb = (const char*)smem + db * 16384 + rowb;
#pragma unroll
    for (int kh = 0; kh < 2; ++kh) {
      f32x4 lo = *(const f32x4*)(lb + ((kh * 8 + 2 * g + 0) ^ key) * 16);
      f32x4 hi = *(const f32x4*)(lb + ((kh * 8 + 2 * g + 1) ^ key) * 16);
      union { short8 s; unsigned int u[4]; } af;
      af.u[0] = cvtpk(lo[0], lo[1]);
      af.u[1] = cvtpk(lo[2], lo[3]);
      af.u[2] = cvtpk(hi[0], hi[1]);
      af.u[3] = cvtpk(hi[2], hi[3]);
      int k = c * 64 + kh * 32 + 8 * g;
#pragma unroll
      for (int ct = 0; ct < 4; ++ct) {
        short8 bf = *(const short8*)(vb + (size_t)(ct * 16 + lr) * NN + k);
        acc[ct] = __builtin_amdgcn_mfma_f32_16x16x32_bf16(af.s, bf, acc[ct], 0, 0, 0);
      }
    }
    __syncthreads();
  }
#undef XVSTAGE

  float* ab = a + ((size_t)b * MM + m0 + w * 16) * 64;
#pragma unroll
  for (int ct = 0; ct < 4; ++ct)
#pragma unroll
    for (int j = 0; j < 4; ++j)
      ab[(size_t)(4 * g + j) * 64 + ct * 16 + lr] = acc[ct][j];
}

// a[b][n][r] = sum_m x[b][m][n] * u[b][m][r];  uT = [B,64,M] bf16  (r9 body)
__global__ void __launch_bounds__(256, 2)
gemm_xtu(const float* __restrict__ x,
         const unsigned short* __restrict__ uT,
         float* __restrict__ a) {
  __shared__ char smem[32768];
  int b = (BB - 1) - blockIdx.y;
  int n0 = blockIdx.x * 64;
  int tid = threadIdx.x;
  int w = tid >> 6, l = tid & 63;
  int lr = l & 15, g = l >> 4;
  const unsigned short* ub = uT + (size_t)b * 64 * MM;
  const char* xg0 = (const char*)x + ((size_t)b * MM * NN + n0) * 4;
  f32x4 acc[4] = {};
  int slotX = ((w * 4 + (lr >> 2)) ^ ((g & 1) << 2)) * 16 + (lr & 3) * 4;

#define XTSTAGE(DB, CH)                                                         \
  {                                                                             \
    char* lbs = (char*)smem + (DB)*16384;                                       \
    _Pragma("unroll")                                                           \
    for (int i = 0; i < 4; ++i) {                                               \
      int s = w * 4 + i;                                                        \
      int lg = ((l & 15) ^ (((s >> 1) & 1) << 2)) * 16;                         \
      const char* gp = xg0 + (size_t)((CH)*64 + s * 4 + (l >> 4)) * (NN * 4) +  \
                       lg;                                                      \
      __builtin_amdgcn_global_load_lds(                                         \
          (const __attribute__((address_space(1))) unsigned int*)gp,            \
          (__attribute__((address_space(3))) unsigned int*)(lbs + s * 1024),    \
          16, 0, 0);                                                            \
    }                                                                           \
  }

  XTSTAGE(0, 0);
  __syncthreads();
  for (int c = 0; c < 32; ++c) {
    int db = c & 1;
    if (c + 1 < 32) XTSTAGE(db ^ 1, c + 1);
    const char* lb = (const char*)smem + db * 16384 + slotX;
#pragma unroll
    for (int kh = 0; kh < 2; ++kh) {
      const char* lk = lb + (kh * 32 + 8 * g) * 256;
      float vv[8];
#pragma unroll
      for (int j = 0; j < 8; ++j)
        vv[j] = *(const float*)(lk + j * 256);
      union { short8 s; unsigned int u[4]; } af;
      af.u[0] = cvtpk(vv[0], vv[1]);
      af.u[1] = cvtpk(vv[2], vv[3]);
      af.u[2] = cvtpk(vv[4], vv[5]);
      af.u[3] = cvtpk(vv[6], vv[7]);
      int k = c * 64 + kh * 32 + 8 * g;
#pragma unroll
      for (int ct = 0; ct < 4; ++ct) {
        short8 bf = *(const short8*)(ub + (size_t)(ct * 16 + lr) * MM + k);
        acc[ct] = __builtin_amdgcn_mfma_f32_16x16x32_bf16(af.s, bf, acc[ct], 0, 0, 0);
      }
    }
    __syncthreads();
  }
#undef XTSTAGE

  float* ab = a + ((size_t)b * NN + n0 + w * 16) * 64;
#pragma unroll
  for (int ct = 0; ct < 4; ++ct)
#pragma unroll
    for (int j = 0; j < 4; ++j)
      ab[(size_t)(4 * g + j) * 64 + ct * 16 + lr] = acc[ct][j];
}

// Coordinate descent, one THREAD per row. grid (nrows/64, B), block 64.
__global__ void __launch_bounds__(64, 1)
cd_kernel2(const float* __restrict__ u_in,
           const float* __restrict__ a_ws,
           const float* __restrict__ bmat,
           float* __restrict__ u_out,
           float l1, float l2e, int nrows) {
  int b = blockIdx.y;
  int m = blockIdx.x * 64 + threadIdx.x;
  size_t base = ((size_t)b * nrows + m) * 64;
  const float* bb = bmat + b * 4096;
  float uu[64], aa[64];
#pragma unroll
  for (int i = 0; i < 16; ++i) {
    *(f32x4*)(uu + 4 * i) = *(const f32x4*)(u_in + base + 4 * i);
    *(f32x4*)(aa + 4 * i) = *(const f32x4*)(a_ws + base + 4 * i);
  }
  int lane = threadIdx.x;
  float invl = 1.0f / (bb[lane * 65] + l2e);
#pragma unroll
  for (int r = 0; r < 64; ++r) {
    float s0 = 0.f, s1 = 0.f, s2 = 0.f, s3 = 0.f;
#pragma unroll
    for (int j = 0; j < 64; j += 4) {
      s0 = fmaf(uu[j + 0], bb[r * 64 + j + 0], s0);
      s1 = fmaf(uu[j + 1], bb[r * 64 + j + 1], s1);
      s2 = fmaf(uu[j + 2], bb[r * 64 + j + 2], s2);
      s3 = fmaf(uu[j + 3], bb[r * 64 + j + 3], s3);
    }
    float s = (s0 + s1) + (s2 + s3);
    float brr = bb[r * 65];
    float num = fmaf(uu[r], brr, aa[r] - s);
    float cl = fminf(fmaxf(num, -l1), l1);
    uu[r] = (num - cl) * rdlane(invl, r);
  }
#pragma unroll
  for (int i = 0; i < 16; ++i)
    *(f32x4*)(u_out + base + 4 * i) = *(const f32x4*)(uu + 4 * i);
}

// PROBE 1: fully-coalesced sequential grid-stride read of all of x.
// No writes (asm sink); compiler memory-barrier between reps prevents
// load merging. grid 2048 x 256 (8 blocks/CU, max TLP).
__global__ void __launch_bounds__(256, 8)
probe_seq(const float* __restrict__ x, int reps) {
  size_t tid = (size_t)blockIdx.x * 256 + threadIdx.x;
  size_t nthreads = (size_t)gridDim.x * 256;
  const float4* xv = (const float4*)x;
  size_t total = (size_t)BB * MM * NN / 4;
  float ax = 0.f, ay = 0.f, az = 0.f, aw = 0.f;
  for (int r = 0; r < reps; ++r) {
    for (size_t i = tid; i < total; i += nthreads) {
      float4 t = xv[i];
      ax += t.x; ay += t.y; az += t.z; aw += t.w;
    }
    asm volatile("" ::: "memory");
  }
  asm volatile("" :: "v"(ax), "v"(ay), "v"(az), "v"(aw));
}

// PROBE 2: exact r9-xv x address pattern (4 rows x 256B per wave-inst,
// 8KB row stride, 512 blocks = 2/CU) but NO LDS/MFMA/barriers.
__global__ void __launch_bounds__(256, 2)
probe_strided(const float* __restrict__ x, int reps) {
  int b = blockIdx.y;
  int m0 = blockIdx.x * 64;
  int tid = threadIdx.x;
  int w = tid >> 6, l = tid & 63;
  const float* base = x + (size_t)b * MM * NN + (size_t)m0 * NN;
  float ax = 0.f, ay = 0.f, az = 0.f, aw = 0.f;
  for (int r = 0; r < reps; ++r) {
    for (int c = 0; c < 32; ++c) {
#pragma unroll
      for (int i = 0; i < 4; ++i) {
        int row = w * 16 + i * 4 + (l >> 4);
        int col = c * 64 + (l & 15) * 4;
        float4 t = *(const float4*)(base + (size_t)row * NN + col);
        ax += t.x; ay += t.y; az += t.z; aw += t.w;
      }
    }
    asm volatile("" ::: "memory");
  }
  asm volatile("" :: "v"(ax), "v"(ay), "v"(az), "v"(aw));
}

extern "C" void kernel_launch(void* const* d_in, const int* in_sizes, int n_in,
                              void* d_out, int out_size, void* d_ws, size_t ws_size,
                              hipStream_t stream) {
  (void)in_sizes; (void)n_in; (void)out_size; (void)ws_size;
  const float* x = (const float*)d_in[0];
  const float* u = (const float*)d_in[1];
  const float* v = (const float*)d_in[2];
  float* u_out = (float*)d_out;
  float* v_out = u_out + (size_t)BB * MM * 64;

  float* a_ws = (float*)d_ws;                                        // 8.39 MB
  float* b_ws = (float*)((char*)d_ws + (size_t)BB * MM * 64 * 4);    // 256 KB
  unsigned short* tT = (unsigned short*)((char*)b_ws + (size_t)BB * 4096 * 4);

  float l1u = (float)(0.01 * 0.1 * (double)NN);
  float l2u = (float)(0.01 * 0.9 * (double)NN + 1e-16);
  float l1v = (float)(0.01 * 0.1 * (double)MM);
  float l2v = (float)(0.01 * 0.9 * (double)MM + 1e-16);

  // ---- canonical pipeline (r9 bodies, 255 us) ----
  transpose_cvt<<<dim3(NN / 64, BB), 256, 0, stream>>>(v, tT, NN);
  gemm_gram2<<<dim3(BB), 256, 0, stream>>>(tT, b_ws, NN);
  gemm_xv<<<dim3(MM / 64, BB), 256, 0, stream>>>(x, tT, a_ws);
  cd_kernel2<<<dim3(MM / 64, BB), 64, 0, stream>>>(u, a_ws, b_ws, u_out, l1u, l2u, MM);

  transpose_cvt<<<dim3(MM / 64, BB), 256, 0, stream>>>(u_out, tT, MM);
  gemm_gram2<<<dim3(BB), 256, 0, stream>>>(tT, b_ws, MM);
  gemm_xtu<<<dim3(NN / 64, BB), 256, 0, stream>>>(x, tT, a_ws);
  cd_kernel2<<<dim3(NN / 64, BB), 64, 0, stream>>>(v, a_ws, b_ws, v_out, l1v, l2v, NN);

  // ---- measurement probes (no writes; deterministic) ----
  probe_seq<<<dim3(2048), 256, 0, stream>>>(x, 8);
  probe_strided<<<dim3(MM / 64, BB), 256, 0, stream>>>(x, 3);
}

// Round 14
// 269.846 us; speedup vs baseline: 2.5608x; 2.5608x over previous
//
#include <hip/hip_runtime.h>

typedef __attribute__((ext_vector_type(8))) short short8;
typedef __attribute__((ext_vector_type(4))) float f32x4;

#define BB 16
#define MM 2048
#define NN 2048
#define APSF ((size_t)BB * 2048 * 64)   // floats per partial a-buffer

static __device__ __forceinline__ unsigned int cvtpk(float lo, float hi) {
  unsigned int r;
  asm("v_cvt_pk_bf16_f32 %0, %1, %2" : "=v"(r) : "v"(lo), "v"(hi));
  return r;
}
static __device__ __forceinline__ float rdlane(float v, int l) {
  return __uint_as_float(__builtin_amdgcn_readlane(__float_as_uint(v), l));
}

// in: [B, nrows, 64] f32 -> out: [B, 64, nrows] bf16
__global__ void transpose_cvt(const float* __restrict__ in,
                              unsigned short* __restrict__ out, int nrows) {
  __shared__ float t[64][65];
  int b = blockIdx.y;
  int n0 = blockIdx.x * 64;
  int tid = threadIdx.x;
  int lane = tid & 63;
  int q = tid >> 6;
  const float* inb = in + ((size_t)b * nrows + n0) * 64;
#pragma unroll
  for (int i = 0; i < 16; ++i) {
    int n = q * 16 + i;
    t[n][lane] = inb[n * 64 + lane];
  }
  __syncthreads();
  unsigned short* outb = out + (size_t)b * 64 * nrows + n0;
  int pr = tid & 31, rq = tid >> 5;
#pragma unroll
  for (int i = 0; i < 8; ++i) {
    int r = rq + 8 * i;
    int n = 2 * pr;
    *(unsigned int*)(outb + (size_t)r * nrows + n) = cvtpk(t[n][r], t[n + 1][r]);
  }
}

// Gram: bmat[b] = T * T^T, T = [64, K] bf16 row-major. grid (B), block 256.
__global__ void gemm_gram2(const unsigned short* __restrict__ tT,
                           float* __restrict__ bmat, int K) {
  __shared__ float part[4][64][65];
  int b = blockIdx.x;
  int tid = threadIdx.x;
  int w = tid >> 6, l = tid & 63;
  int lr = l & 15, g = l >> 4;
  const unsigned short* vb = tT + (size_t)b * 64 * K;
  int kslice = K >> 2;
  int kbase = w * kslice;
  f32x4 acc[4][4] = {};
  for (int kk = 0; kk < kslice; kk += 32) {
    int k = kbase + kk + 8 * g;
    short8 fr[4];
#pragma unroll
    for (int rt = 0; rt < 4; ++rt)
      fr[rt] = *(const short8*)(vb + (size_t)(rt * 16 + lr) * K + k);
#pragma unroll
    for (int rt = 0; rt < 4; ++rt)
#pragma unroll
      for (int ct = 0; ct < 4; ++ct)
        acc[rt][ct] = __builtin_amdgcn_mfma_f32_16x16x32_bf16(fr[rt], fr[ct], acc[rt][ct], 0, 0, 0);
  }
#pragma unroll
  for (int rt = 0; rt < 4; ++rt)
#pragma unroll
    for (int ct = 0; ct < 4; ++ct)
#pragma unroll
      for (int j = 0; j < 4; ++j)
        part[w][rt * 16 + 4 * g + j][ct * 16 + lr] = acc[rt][ct][j];
  __syncthreads();
  float* bb = bmat + b * 4096;
  for (int i = tid; i < 4096; i += 256) {
    int row = i >> 6, col = i & 63;
    bb[i] = part[0][row][col] + part[1][row][col] + part[2][row][col] + part[3][row][col];
  }
}

// a[b][m][r] = sum_n x[b][m][n] * v[b][n][r];  vT = [B,64,N] bf16
// REG-STAGED (probe-proven ~7 TB/s path): plain float4 loads -> VGPRs ->
// ds_write_b128 into the SAME swizzled layout r9's DMA produced
// (phys slot p = q ^ ((s&1)*4+(l>>4)), involution). K-split 2 -> grid 1024
// = 4 blocks/CU (16 waves/CU keep ~1 chunk each in flight across barriers).
// grid (M/64, 2, B), block 256; partials to ap[kq].
__global__ void __launch_bounds__(256, 4)
gemm_xv(const float* __restrict__ x,
        const unsigned short* __restrict__ vT,
        float* __restrict__ ap) {
  __shared__ char smem[32768];  // 2 x 16 KB
  int b = blockIdx.z;
  int kq = blockIdx.y;
  int m0 = blockIdx.x * 64;
  int tid = threadIdx.x;
  int w = tid >> 6, l = tid & 63;
  int lr = l & 15, g = l >> 4;
  const unsigned short* vb = vT + (size_t)b * 64 * NN + kq * 1024;
  const char* xg0 = (const char*)x + ((size_t)b * MM + m0) * (size_t)(NN * 4) + kq * 4096;
  float* aq = ap + (size_t)kq * APSF;
  f32x4 acc[4] = {};
  f32x4 st[4];
  int rowb = (w * 16 + lr) * 256;
  int key = lr & 7;

#define XVLOAD(CH)                                                              \
  {                                                                             \
    _Pragma("unroll")                                                           \
    for (int i = 0; i < 4; ++i) {                                               \
      int s = w * 4 + i;                                                        \
      st[i] = *(const f32x4*)(xg0 + (size_t)(s * 4 + (l >> 4)) * (NN * 4) +     \
                              (CH)*256 + (l & 15) * 16);                        \
    }                                                                           \
  }
#define XVWRITE(DB)                                                             \
  {                                                                             \
    char* lbs = (char*)smem + (DB)*16384;                                       \
    _Pragma("unroll")                                                           \
    for (int i = 0; i < 4; ++i) {                                               \
      int s = w * 4 + i;                                                        \
      int p = (l & 15) ^ ((s & 1) * 4 + (l >> 4));                              \
      *(f32x4*)(lbs + s * 1024 + (l >> 4) * 256 + p * 16) = st[i];              \
    }                                                                           \
  }
#define XVCOMP(C)                                                               \
  {                                                                             \
    const char* lb = (const char*)smem + ((C)&1) * 16384 + rowb;                \
    _Pragma("unroll")                                                           \
    for (int kh = 0; kh < 2; ++kh) {                                            \
      f32x4 lo = *(const f32x4*)(lb + ((kh * 8 + 2 * g + 0) ^ key) * 16);       \
      f32x4 hi = *(const f32x4*)(lb + ((kh * 8 + 2 * g + 1) ^ key) * 16);       \
      union { short8 s; unsigned int u[4]; } af;                                \
      af.u[0] = cvtpk(lo[0], lo[1]);                                            \
      af.u[1] = cvtpk(lo[2], lo[3]);                                            \
      af.u[2] = cvtpk(hi[0], hi[1]);                                            \
      af.u[3] = cvtpk(hi[2], hi[3]);                                            \
      int k = (C)*64 + kh * 32 + 8 * g;                                         \
      _Pragma("unroll")                                                         \
      for (int ct = 0; ct < 4; ++ct) {                                          \
        short8 bf = *(const short8*)(vb + (size_t)(ct * 16 + lr) * NN + k);     \
        acc[ct] = __builtin_amdgcn_mfma_f32_16x16x32_bf16(af.s, bf, acc[ct],    \
                                                          0, 0, 0);             \
      }                                                                         \
    }                                                                           \
  }

  XVLOAD(0);
  XVWRITE(0);
  XVLOAD(1);
  __syncthreads();
  for (int c = 0; c < 16; ++c) {
    if (c + 1 < 16) XVWRITE((c + 1) & 1);  // regs hold chunk c+1
    if (c + 2 < 16) XVLOAD(c + 2);         // issue early; lands during COMP
    XVCOMP(c);
    __syncthreads();
  }
#undef XVLOAD
#undef XVWRITE
#undef XVCOMP

  float* ab = aq + ((size_t)b * MM + m0 + w * 16) * 64;
#pragma unroll
  for (int ct = 0; ct < 4; ++ct)
#pragma unroll
    for (int j = 0; j < 4; ++j)
      ab[(size_t)(4 * g + j) * 64 + ct * 16 + lr] = acc[ct][j];
}

// a[b][n][r] = sum_m x[b][m][n] * u[b][m][r];  uT = [B,64,M] bf16
// Same reg-staged pipeline; swizzle p = q ^ (((s>>1)&1)<<2) (r9 layout).
// K-split 2 over M; batch order reversed for L3. grid (N/64, 2, B), block 256.
__global__ void __launch_bounds__(256, 4)
gemm_xtu(const float* __restrict__ x,
         const unsigned short* __restrict__ uT,
         float* __restrict__ ap) {
  __shared__ char smem[32768];
  int b = (BB - 1) - blockIdx.z;
  int kq = blockIdx.y;
  int n0 = blockIdx.x * 64;
  int tid = threadIdx.x;
  int w = tid >> 6, l = tid & 63;
  int lr = l & 15, g = l >> 4;
  const unsigned short* ubh = uT + (size_t)b * 64 * MM + kq * 1024;
  const char* xg0 = (const char*)x + (((size_t)b * MM + kq * 1024) * NN + n0) * 4;
  float* aq = ap + (size_t)kq * APSF;
  f32x4 acc[4] = {};
  f32x4 st[4];
  int slotX = ((w * 4 + (lr >> 2)) ^ ((g & 1) << 2)) * 16 + (lr & 3) * 4;

#define XTLOAD(CH)                                                              \
  {                                                                             \
    _Pragma("unroll")                                                           \
    for (int i = 0; i < 4; ++i) {                                               \
      int s = w * 4 + i;                                                        \
      st[i] = *(const f32x4*)(xg0 +                                             \
                              (size_t)((CH)*64 + s * 4 + (l >> 4)) * (NN * 4) + \
                              (l & 15) * 16);                                   \
    }                                                                           \
  }
#define XTWRITE(DB)                                                             \
  {                                                                             \
    char* lbs = (char*)smem + (DB)*16384;                                       \
    _Pragma("unroll")                                                           \
    for (int i = 0; i < 4; ++i) {                                               \
      int s = w * 4 + i;                                                        \
      int p = (l & 15) ^ (((s >> 1) & 1) << 2);                                 \
      *(f32x4*)(lbs + s * 1024 + (l >> 4) * 256 + p * 16) = st[i];              \
    }                                                                           \
  }
#define XTCOMP(C)                                                               \
  {                                                                             \
    const char* lb = (const char*)smem + ((C)&1) * 16384 + slotX;               \
    _Pragma("unroll")                                                           \
    for (int kh = 0; kh < 2; ++kh) {                                            \
      const char* lk = lb + (kh * 32 + 8 * g) * 256;                            \
      float vv[8];                                                              \
      _Pragma("unroll")                                                         \
      for (int j = 0; j < 8; ++j)                                               \
        vv[j] = *(const float*)(lk + j * 256);                                  \
      union { short8 s; unsigned int u[4]; } af;                                \
      af.u[0] = cvtpk(vv[0], vv[1]);                                            \
      af.u[1] = cvtpk(vv[2], vv[3]);                                            \
      af.u[2] = cvtpk(vv[4], vv[5]);                                            \
      af.u[3] = cvtpk(vv[6], vv[7]);                                            \
      int k = (C)*64 + kh * 32 + 8 * g;                                         \
      _Pragma("unroll")                                                         \
      for (int ct = 0; ct < 4; ++ct) {                                          \
        short8 bf = *(const short8*)(ubh + (size_t)(ct * 16 + lr) * MM + k);    \
        acc[ct] = __builtin_amdgcn_mfma_f32_16x16x32_bf16(af.s, bf, acc[ct],    \
                                                          0, 0, 0);             \
      }                                                                         \
    }                                                                           \
  }

  XTLOAD(0);
  XTWRITE(0);
  XTLOAD(1);
  __syncthreads();
  for (int c = 0; c < 16; ++c) {
    if (c + 1 < 16) XTWRITE((c + 1) & 1);
    if (c + 2 < 16) XTLOAD(c + 2);
    XTCOMP(c);
    __syncthreads();
  }
#undef XTLOAD
#undef XTWRITE
#undef XTCOMP

  float* ab = aq + ((size_t)b * NN + n0 + w * 16) * 64;
#pragma unroll
  for (int ct = 0; ct < 4; ++ct)
#pragma unroll
    for (int j = 0; j < 4; ++j)
      ab[(size_t)(4 * g + j) * 64 + ct * 16 + lr] = acc[ct][j];
}

// Coordinate descent, one THREAD per row; a = p0 + p1 (deterministic).
// grid (nrows/64, B), block 64.
__global__ void __launch_bounds__(64, 1)
cd_sum2(const float* __restrict__ u_in,
        const float* __restrict__ ap,
        const float* __restrict__ bmat,
        float* __restrict__ u_out,
        float l1, float l2e, int nrows) {
  int b = blockIdx.y;
  int m = blockIdx.x * 64 + threadIdx.x;
  size_t base = ((size_t)b * nrows + m) * 64;
  const float* bb = bmat + b * 4096;
  float uu[64], aa[64];
#pragma unroll
  for (int i = 0; i < 16; ++i) {
    *(f32x4*)(uu + 4 * i) = *(const f32x4*)(u_in + base + 4 * i);
    f32x4 p0 = *(const f32x4*)(ap + base + 4 * i);
    f32x4 p1 = *(const f32x4*)(ap + APSF + base + 4 * i);
    *(f32x4*)(aa + 4 * i) = p0 + p1;
  }
  int lane = threadIdx.x;
  float invl = 1.0f / (bb[lane * 65] + l2e);
#pragma unroll
  for (int r = 0; r < 64; ++r) {
    float s0 = 0.f, s1 = 0.f, s2 = 0.f, s3 = 0.f;
#pragma unroll
    for (int j = 0; j < 64; j += 4) {
      s0 = fmaf(uu[j + 0], bb[r * 64 + j + 0], s0);
      s1 = fmaf(uu[j + 1], bb[r * 64 + j + 1], s1);
      s2 = fmaf(uu[j + 2], bb[r * 64 + j + 2], s2);
      s3 = fmaf(uu[j + 3], bb[r * 64 + j + 3], s3);
    }
    float s = (s0 + s1) + (s2 + s3);
    float brr = bb[r * 65];                      // uniform -> SGPR
    float num = fmaf(uu[r], brr, aa[r] - s);     // a_r - (s - u_r*b_rr)
    float cl = fminf(fmaxf(num, -l1), l1);       // v_med3
    uu[r] = (num - cl) * rdlane(invl, r);
  }
#pragma unroll
  for (int i = 0; i < 16; ++i)
    *(f32x4*)(u_out + base + 4 * i) = *(const f32x4*)(uu + 4 * i);
}

extern "C" void kernel_launch(void* const* d_in, const int* in_sizes, int n_in,
                              void* d_out, int out_size, void* d_ws, size_t ws_size,
                              hipStream_t stream) {
  (void)in_sizes; (void)n_in; (void)out_size; (void)ws_size;
  const float* x = (const float*)d_in[0];
  const float* u = (const float*)d_in[1];
  const float* v = (const float*)d_in[2];
  float* u_out = (float*)d_out;
  float* v_out = u_out + (size_t)BB * MM * 64;

  float* ap = (float*)d_ws;                          // 2 x 8.39 MB partials
  float* b_ws = ap + 2 * APSF;                       // 256 KB
  unsigned short* tT = (unsigned short*)(b_ws + (size_t)BB * 4096);

  float l1u = (float)(0.01 * 0.1 * (double)NN);
  float l2u = (float)(0.01 * 0.9 * (double)NN + 1e-16);
  float l1v = (float)(0.01 * 0.1 * (double)MM);
  float l2v = (float)(0.01 * 0.9 * (double)MM + 1e-16);

  // ---- factor 0: update u ----
  transpose_cvt<<<dim3(NN / 64, BB), 256, 0, stream>>>(v, tT, NN);
  gemm_gram2<<<dim3(BB), 256, 0, stream>>>(tT, b_ws, NN);
  gemm_xv<<<dim3(MM / 64, 2, BB), 256, 0, stream>>>(x, tT, ap);
  cd_sum2<<<dim3(MM / 64, BB), 64, 0, stream>>>(u, ap, b_ws, u_out, l1u, l2u, MM);

  // ---- factor 1: update v (uses new u) ----
  transpose_cvt<<<dim3(MM / 64, BB), 256, 0, stream>>>(u_out, tT, MM);
  gemm_gram2<<<dim3(BB), 256, 0, stream>>>(tT, b_ws, MM);
  gemm_xtu<<<dim3(NN / 64, 2, BB), 256, 0, stream>>>(x, tT, ap);
  cd_sum2<<<dim3(NN / 64, BB), 64, 0, stream>>>(v, ap, b_ws, v_out, l1v, l2v, NN);
}